// Round 11
// baseline (141.075 us; speedup 1.0000x reference)
//
#include <hip/hip_runtime.h>
#include <hip/hip_bf16.h>
#include <cstddef>

#define BB 4
#define CC 64
#define UU 5
#define VV 5
#define HH 64
#define WW 64
#define NIJ (69*69)   // 4761

typedef float f4v __attribute__((ext_vector_type(4)));

__device__ __forceinline__ float rdlane(float v, int l) {
    return __uint_as_float((unsigned)__builtin_amdgcn_readlane((int)__float_as_uint(v), l));
}
__device__ __forceinline__ float rfl(float v) {
    return __uint_as_float((unsigned)__builtin_amdgcn_readfirstlane((int)__float_as_uint(v)));
}
__device__ __forceinline__ float sum4(float4 a) { return (a.x+a.y)+(a.z+a.w); }
__device__ __forceinline__ void nt_store4(float4 r, float4* p) {
    union { float4 s; f4v v; } u; u.s = r;
    __builtin_nontemporal_store(u.v, (f4v*)p);
}

// ---------------------------------------------------------------------------
// K1: 512 blocks = (bc, h-half), 512 threads, __launch_bounds__(512,8)
// -> VGPR<=64 -> 8 waves/SIMD (32/CU) for latency hiding (k1 is latency-bound:
// R1 counters showed VALUBusy 3.8%, occupancy 18%).
// Minimal per-thread state: hw(4) + vwacc(20). Row-sums R[u,v,h] written to
// global per tile (uh/uv derived in k1b from R).
//   m_hw[bc][p]            final /25
//   R[bc][k][h]            UNSCALED row sums (sum over w)
//   vw_part[bid][v][wq]f4  UNSCALED col sums over block's 32 h
// Scratch lives in d_out (k3 rewrites it).
// ---------------------------------------------------------------------------
__global__ __launch_bounds__(512, 8) void k1_means(const float* __restrict__ x,
        float* __restrict__ m_hw, float* __restrict__ R,
        float* __restrict__ vw_part) {
    const int bid  = blockIdx.x;      // bc*2 + half
    const int bc   = bid >> 1;
    const int half = bid & 1;
    const int t    = threadIdx.x;     // 0..511
    const int p    = half*512 + t;    // quad index in tile, 0..1023
    const int wave = t >> 6;
    const int lane = t & 63;

    const float4* xt = (const float4*)x + (size_t)bc * 25600;

    __shared__ float4 vw_lds[8][5][16];

    float4 hw = make_float4(0.f,0.f,0.f,0.f);
    float4 vwacc[5];
    #pragma unroll
    for (int v = 0; v < 5; ++v) vwacc[v] = make_float4(0.f,0.f,0.f,0.f);

    #pragma unroll
    for (int u = 0; u < 5; ++u) {
        #pragma unroll
        for (int v = 0; v < 5; ++v) {
            float4 q = xt[(u*5 + v)*1024 + p];
            hw.x += q.x; hw.y += q.y; hw.z += q.z; hw.w += q.w;
            vwacc[v].x += q.x; vwacc[v].y += q.y;
            vwacc[v].z += q.z; vwacc[v].w += q.w;
            float s4 = sum4(q);
            s4 += __shfl_xor(s4, 1); s4 += __shfl_xor(s4, 2);
            s4 += __shfl_xor(s4, 4); s4 += __shfl_xor(s4, 8);
            if ((t & 15) == 0)
                R[((size_t)bc*25 + u*5 + v)*64 + (p >> 4)] = s4;
        }
    }

    // hw final (sum over all 25 tiles at quad p), /25
    float4 o;
    o.x = hw.x*(1.f/25.f); o.y = hw.y*(1.f/25.f);
    o.z = hw.z*(1.f/25.f); o.w = hw.w*(1.f/25.f);
    ((float4*)m_hw)[(size_t)bc*1024 + p] = o;

    // vw: reduce over this wave's 4 h-rows
    #pragma unroll
    for (int v = 0; v < 5; ++v) {
        float4 s = vwacc[v];
        s.x += __shfl_xor(s.x, 16); s.y += __shfl_xor(s.y, 16);
        s.z += __shfl_xor(s.z, 16); s.w += __shfl_xor(s.w, 16);
        s.x += __shfl_xor(s.x, 32); s.y += __shfl_xor(s.y, 32);
        s.z += __shfl_xor(s.z, 32); s.w += __shfl_xor(s.w, 32);
        if (lane < 16) vw_lds[wave][v][lane] = s;
    }
    __syncthreads();

    if (t < 80) {   // fold 8 waves -> per-(bc,half) vw partial (32 h rows)
        const int v = t >> 4;
        float4 s = vw_lds[0][v][t & 15];
        #pragma unroll
        for (int w8 = 1; w8 < 8; ++w8) {
            float4 pp = vw_lds[w8][v][t & 15];
            s.x += pp.x; s.y += pp.y; s.z += pp.z; s.w += pp.w;
        }
        ((float4*)vw_part)[(size_t)bid*80 + t] = s;
    }
}

// ---------------------------------------------------------------------------
// K1b: 276 blocks, 256 threads.
// blk<256: (b,h) -> transpose m_hw row; uh border = sum_v R / 320.
// blk>=256: (b,v) -> fold vw halves, transpose; uv border = sum_h R / 4096.
// ---------------------------------------------------------------------------
__global__ __launch_bounds__(256) void k1b_assemble(
        const float* __restrict__ m_hw, const float* __restrict__ R,
        const float* __restrict__ vw_part, float* __restrict__ grid_t) {
    __shared__ float tile[64][68];
    const int blk = blockIdx.x;
    const bool top = blk < 256;
    const int t = threadIdx.x;        // 0..255
    const int c = t >> 2;             // 0..63
    const int qs = t & 3;             // 0..3

    int b, i;
    if (top) {
        b = blk >> 6;
        const int h = blk & 63;
        i = h;
        #pragma unroll
        for (int j = 0; j < 4; ++j) {
            const int q = 4*j + qs;   // 0..15
            float4 v = ((const float4*)m_hw)[((size_t)(b*64 + c))*1024 + h*16 + q];
            const int w = q * 4;
            tile[w+0][c] = v.x; tile[w+1][c] = v.y;
            tile[w+2][c] = v.z; tile[w+3][c] = v.w;
        }
        // uh border: sum over v of R[bc][u*5+v][h], /320
        for (int idx = t; idx < 320; idx += 256) {
            const int u = idx >> 6, cc = idx & 63;
            const float* Rp = R + (((size_t)(b*64 + cc)*25) + u*5)*64 + h;
            float s = Rp[0] + Rp[64] + Rp[128] + Rp[192] + Rp[256];
            grid_t[((size_t)b*NIJ + h*69 + 64 + u)*64 + cc] = s * (1.f/320.f);
        }
    } else {
        b = (blk - 256) / 5;
        const int v = (blk - 256) % 5;
        i = 64 + v;
        #pragma unroll
        for (int j = 0; j < 4; ++j) {
            const int wq = 4*j + qs;
            float4 p0 = ((const float4*)vw_part)[((size_t)(b*64 + c)*2 + 0)*80 + v*16 + wq];
            float4 p1 = ((const float4*)vw_part)[((size_t)(b*64 + c)*2 + 1)*80 + v*16 + wq];
            const int w = wq * 4;
            const float sc = 1.f/320.f;
            tile[w+0][c] = (p0.x + p1.x)*sc; tile[w+1][c] = (p0.y + p1.y)*sc;
            tile[w+2][c] = (p0.z + p1.z)*sc; tile[w+3][c] = (p0.w + p1.w)*sc;
        }
        // uv border: sum over h of R[bc][u*5+v][h], /4096
        for (int idx = t; idx < 320; idx += 256) {
            const int u = idx >> 6, cc = idx & 63;
            const float4* Rp4 = (const float4*)(R + (((size_t)(b*64 + cc)*25) + u*5 + v)*64);
            float4 a = make_float4(0.f,0.f,0.f,0.f);
            #pragma unroll
            for (int k = 0; k < 16; ++k) {
                float4 pp = Rp4[k];
                a.x += pp.x; a.y += pp.y; a.z += pp.z; a.w += pp.w;
            }
            grid_t[((size_t)b*NIJ + i*69 + 64 + u)*64 + cc] = sum4(a) * (1.f/4096.f);
        }
    }
    __syncthreads();

    float4* dst4 = (float4*)grid_t + ((size_t)b*NIJ + i*69) * 16;
    #pragma unroll
    for (int k = 0; k < 4; ++k) {
        const int oidx = k*256 + t;   // 0..1023
        const int w = oidx >> 4, cq = (oidx & 15) * 4;
        float4 v;
        v.x = tile[w][cq]; v.y = tile[w][cq+1];
        v.z = tile[w][cq+2]; v.w = tile[w][cq+3];
        dst4[oidx] = v;
    }
}

// ---------------------------------------------------------------------------
// K2: per-position MLP + region conv.
// grid = 276 rows x 4 chunks = 1104 blocks, 64 threads (one wave, ~17 cols).
// __launch_bounds__(64, 1): weight arrays stay in VGPRs (R2 lesson).
// ---------------------------------------------------------------------------
#define LOADROW(dst, src)                                              \
    { _Pragma("unroll")                                                \
      for (int q = 0; q < 16; ++q) {                                   \
          float4 t4 = ((const float4*)(src))[lane*16 + q];             \
          dst[4*q+0] = t4.x; dst[4*q+1] = t4.y;                        \
          dst[4*q+2] = t4.z; dst[4*q+3] = t4.w;                        \
      } }

#define DOT64(res, wr, src)                                            \
    float res;                                                         \
    { float _a0=0.f,_a1=0.f,_a2=0.f,_a3=0.f;                           \
      _Pragma("unroll")                                                \
      for (int cc2 = 0; cc2 < 64; cc2 += 4) {                          \
          _a0 = fmaf(wr[cc2+0], rdlane(src, cc2+0), _a0);              \
          _a1 = fmaf(wr[cc2+1], rdlane(src, cc2+1), _a1);              \
          _a2 = fmaf(wr[cc2+2], rdlane(src, cc2+2), _a2);              \
          _a3 = fmaf(wr[cc2+3], rdlane(src, cc2+3), _a3);              \
      }                                                                \
      res = (_a0 + _a1) + (_a2 + _a3); }

#define MLP_BODY(J)                                                    \
    {                                                                  \
        const int jj = (J);                                            \
        float v = gtb[(size_t)(i*69 + jj) * CC + lane];                \
        DOT64(d1, w1r, v);                                             \
        float acc1 = d1 + b1v;                                         \
        float ya = acc1 / (1.f + __expf(-acc1));                       \
        DOT64(d2, w2r, ya);                                            \
        float acc2 = d2 + b2v;                                         \
        DOT64(d3, fr, acc2);                                           \
        sp[(size_t)(jj - jbase) * sstr] = d3 + fbv;                    \
    }

__global__ __launch_bounds__(64, 1) void k2_mlp(
        const float* __restrict__ grid_t,
        const float* __restrict__ w1, const float* __restrict__ b1,
        const float* __restrict__ w2, const float* __restrict__ b2,
        const float* __restrict__ fw0, const float* __restrict__ fb0,
        const float* __restrict__ fw1, const float* __restrict__ fb1,
        const float* __restrict__ fw2, const float* __restrict__ fb2,
        const float* __restrict__ fw3, const float* __restrict__ fb3,
        float* __restrict__ mod_hw, float* __restrict__ mod_uh,
        float* __restrict__ mod_vw, float* __restrict__ mod_uv) {
    const int blk  = blockIdx.x;          // row*4 + chunk
    const int row  = blk >> 2;            // 0..275
    const int chnk = blk & 3;
    const int b    = row / 69;
    const int i    = row % 69;
    const int lane = threadIdx.x & 63;

    const int j0 = chnk * 18;
    const int j1 = min(69, j0 + 18);
    const bool top = (i < 64);

    const float* fwA = top ? fw0 : fw3;
    const float* fbA = top ? fb0 : fb3;
    const float* fwB = top ? fw2 : fw1;
    const float* fbB = top ? fb2 : fb1;

    float w1r[64], w2r[64], fr[64];
    LOADROW(w1r, w1);
    LOADROW(w2r, w2);
    const float b1v = b1[lane];
    const float b2v = b2[lane];

    const float* gtb = grid_t + (size_t)b * NIJ * CC;
    const int cbl = b * CC + lane;

    const int jm = min(j1, 64);
    if (j0 < jm) {                        // region A: j < 64
        LOADROW(fr, fwA);
        const float fbv = fbA[lane];
        float* sp; int sstr; const int jbase = 0;
        if (top) { sp = mod_hw + ((size_t)cbl*64 + i)*64;          sstr = 1; }
        else     { sp = mod_vw + (size_t)cbl*320 + (i-64)*64;      sstr = 1; }
        for (int j = j0; j < jm; ++j) MLP_BODY(j)
    }
    if (j1 > 64) {                        // region B: j >= 64
        LOADROW(fr, fwB);
        const float fbv = fbB[lane];
        float* sp; int sstr; const int jbase = 64;
        if (top) { sp = mod_uh + (size_t)cbl*320 + i;              sstr = 64; }
        else     { sp = mod_uv + (size_t)cbl*25 + (i-64);          sstr = 5;  }
        const int jb = max(j0, 64);
        for (int j = jb; j < j1; ++j) MLP_BODY(j)
    }
}

// ---------------------------------------------------------------------------
// K3: out = x * (mod_hw + mod_uv + mod_uh + mod_vw)
// 1024 blocks = (bc, quarter), 256 threads, 4 blocks/CU; uv via readfirstlane.
// ---------------------------------------------------------------------------
__global__ __launch_bounds__(256, 4) void k3_apply(
        const float* __restrict__ x,
        const float* __restrict__ mod_hw, const float* __restrict__ mod_uh,
        const float* __restrict__ mod_vw, const float* __restrict__ mod_uv,
        float* __restrict__ out) {
    const int blk  = blockIdx.x;          // bc*4 + quarter
    const int bc   = blk >> 2;
    const int qt   = blk & 3;
    const int t    = threadIdx.x;         // 0..255
    const int base = qt*256 + t;          // quad index in tile, 0..1023
    const int h    = base >> 4;           // 0..63

    float4 mh = ((const float4*)(mod_hw + (size_t)bc * 4096))[base];
    float uh[5];
    #pragma unroll
    for (int u = 0; u < 5; ++u) uh[u] = mod_uh[(size_t)bc*320 + u*64 + h];
    float4 vw[5];
    #pragma unroll
    for (int v = 0; v < 5; ++v)
        vw[v] = ((const float4*)(mod_vw + (size_t)bc*320 + v*64))[t & 15];
    float uv[25];
    #pragma unroll
    for (int k = 0; k < 25; ++k)
        uv[k] = rfl(mod_uv[(size_t)bc*25 + k]);   // uniform -> SGPR

    const float4* x4 = (const float4*)(x + (size_t)bc * (UU*VV*HH*WW));
    float4* o4 = (float4*)(out + (size_t)bc * (UU*VV*HH*WW));

    #pragma unroll
    for (int u = 0; u < 5; ++u) {
        #pragma unroll
        for (int v = 0; v < 5; ++v) {
            const int idx = (u*5 + v)*1024 + base;
            float4 xv = x4[idx];
            const float s = uh[u] + uv[u*5 + v];
            float4 r;
            r.x = xv.x * (mh.x + vw[v].x + s);
            r.y = xv.y * (mh.y + vw[v].y + s);
            r.z = xv.z * (mh.z + vw[v].z + s);
            r.w = xv.w * (mh.w + vw[v].w + s);
            nt_store4(r, &o4[idx]);
        }
    }
}

// ---------------------------------------------------------------------------
extern "C" void kernel_launch(void* const* d_in, const int* in_sizes, int n_in,
                              void* d_out, int out_size, void* d_ws, size_t ws_size,
                              hipStream_t stream) {
    const float* x   = (const float*)d_in[0];
    const float* w1  = (const float*)d_in[1];
    const float* b1  = (const float*)d_in[2];
    const float* w2  = (const float*)d_in[3];
    const float* b2  = (const float*)d_in[4];
    const float* fw0 = (const float*)d_in[5];
    const float* fb0 = (const float*)d_in[6];
    const float* fw1 = (const float*)d_in[7];
    const float* fb1 = (const float*)d_in[8];
    const float* fw2 = (const float*)d_in[9];
    const float* fb2 = (const float*)d_in[10];
    const float* fw3 = (const float*)d_in[11];
    const float* fb3 = (const float*)d_in[12];

    float* ws = (float*)d_ws;
    float* grid_t = ws;                        // 4*4761*64      = 1,218,816
    float* mod_hw = ws + 1218816;              // 256*4096       = 1,048,576
    float* mod_uh = mod_hw + 1048576;          // 256*320        =    81,920
    float* mod_vw = mod_uh + 81920;            // 256*320        =    81,920
    float* mod_uv = mod_vw + 81920;            // 256*25         =     6,400

    // d_out doubles as scratch for k1 outputs (k3 fully rewrites it).
    float* m_hw    = (float*)d_out;            // 256*4096       = 1,048,576
    float* Rbuf    = m_hw + 1048576;           // 256*25*64      =   409,600
    float* vw_part = Rbuf + 409600;            // 512*320        =   163,840

    k1_means<<<BB*CC*2, 512, 0, stream>>>(x, m_hw, Rbuf, vw_part);
    k1b_assemble<<<BB*CC + BB*VV, 256, 0, stream>>>(m_hw, Rbuf, vw_part, grid_t);
    k2_mlp<<<BB*69*4, 64, 0, stream>>>(grid_t, w1, b1, w2, b2,
                                       fw0, fb0, fw1, fb1, fw2, fb2, fw3, fb3,
                                       mod_hw, mod_uh, mod_vw, mod_uv);
    k3_apply<<<BB*CC*4, 256, 0, stream>>>(x, mod_hw, mod_uh, mod_vw, mod_uv,
                                          (float*)d_out);
}

// Round 12
// 107.981 us; speedup vs baseline: 1.3065x; 1.3065x over previous
//
#include <hip/hip_runtime.h>
#include <hip/hip_bf16.h>
#include <cstddef>

#define BB 4
#define CC 64
#define UU 5
#define VV 5
#define HH 64
#define WW 64
#define NIJ (69*69)   // 4761

typedef float f4v __attribute__((ext_vector_type(4)));

__device__ __forceinline__ float rdlane(float v, int l) {
    return __uint_as_float((unsigned)__builtin_amdgcn_readlane((int)__float_as_uint(v), l));
}
__device__ __forceinline__ float rfl(float v) {
    return __uint_as_float((unsigned)__builtin_amdgcn_readfirstlane((int)__float_as_uint(v)));
}
__device__ __forceinline__ float sum4(float4 a) { return (a.x+a.y)+(a.z+a.w); }
__device__ __forceinline__ void nt_store4(float4 r, float4* p) {
    union { float4 s; f4v v; } u; u.s = r;
    __builtin_nontemporal_store(u.v, (f4v*)p);
}

// ---------------------------------------------------------------------------
// K1 (R12): 512 blocks = (bc, half), 512 threads. SHUFFLE-FREE inner loop:
// per tile = 1 load + 11 VALU + 1 ds_write (no cross-lane, no lgkm waits).
// All reduction deferred behind one barrier (R-phase reads LDS; vw shuffles
// happen ONCE per thread, amortized over 25 loads).
//   m_hw[bc][p]            final /25
//   R[(bc*25+k)*64 + h]    UNSCALED row sums (sum over w); h = half*32+hloc
//   vw_part[bid][v][wq]f4  UNSCALED col sums over block's 32 h
// Scratch lives in d_out (k3 rewrites it). No launch_bounds min-waves
// (R2/R11 lesson: forcing it causes catastrophic VGPR spill).
// ---------------------------------------------------------------------------
__global__ __launch_bounds__(512) void k1_means(const float* __restrict__ x,
        float* __restrict__ m_hw, float* __restrict__ R,
        float* __restrict__ vw_part) {
    const int bid  = blockIdx.x;      // bc*2 + half
    const int bc   = bid >> 1;
    const int half = bid & 1;
    const int t    = threadIdx.x;     // 0..511
    const int p    = half*512 + t;    // quad index in tile, 0..1023
    const int wave = t >> 6;
    const int lane = t & 63;

    const float4* xt = (const float4*)x + (size_t)bc * 25600;

    __shared__ float smem[25*512];    // 51.2 KB: [tile][thread] quad-sums

    float4 hw = make_float4(0.f,0.f,0.f,0.f);
    float4 vwacc[5];
    #pragma unroll
    for (int v = 0; v < 5; ++v) vwacc[v] = make_float4(0.f,0.f,0.f,0.f);

    #pragma unroll
    for (int u = 0; u < 5; ++u) {
        #pragma unroll
        for (int v = 0; v < 5; ++v) {
            float4 q = xt[(u*5 + v)*1024 + p];
            hw.x += q.x; hw.y += q.y; hw.z += q.z; hw.w += q.w;
            vwacc[v].x += q.x; vwacc[v].y += q.y;
            vwacc[v].z += q.z; vwacc[v].w += q.w;
            smem[(u*5 + v)*512 + t] = sum4(q);   // fire-and-forget
        }
    }

    // hw final (this half's 512 quads), /25 — register data, no sync needed
    float4 o;
    o.x = hw.x*(1.f/25.f); o.y = hw.y*(1.f/25.f);
    o.z = hw.z*(1.f/25.f); o.w = hw.w*(1.f/25.f);
    ((float4*)m_hw)[(size_t)bc*1024 + p] = o;

    __syncthreads();

    // Phase B: R row-sums. 800 tasks = 25 tiles x 32 local h.
    for (int task = t; task < 800; task += 512) {
        const int k    = task >> 5;     // tile 0..24
        const int hloc = task & 31;
        const float* row = &smem[k*512 + hloc*16];
        float s = 0.f;
        #pragma unroll
        for (int j = 0; j < 16; ++j) s += row[j];
        R[((size_t)bc*25 + k)*64 + half*32 + hloc] = s;
    }
    __syncthreads();

    // Phase C: vw cross-lane fold (ONCE per thread), reuse smem as float4 buf
    float4* vwbuf = (float4*)smem;    // [wave][v][16]
    #pragma unroll
    for (int v = 0; v < 5; ++v) {
        float4 s = vwacc[v];
        s.x += __shfl_xor(s.x, 16); s.y += __shfl_xor(s.y, 16);
        s.z += __shfl_xor(s.z, 16); s.w += __shfl_xor(s.w, 16);
        s.x += __shfl_xor(s.x, 32); s.y += __shfl_xor(s.y, 32);
        s.z += __shfl_xor(s.z, 32); s.w += __shfl_xor(s.w, 32);
        if (lane < 16) vwbuf[(wave*5 + v)*16 + lane] = s;
    }
    __syncthreads();

    // Phase D: fold 8 waves -> per-(bc,half) vw partial
    if (t < 80) {
        const int v = t >> 4;
        float4 s = vwbuf[(0*5 + v)*16 + (t & 15)];
        #pragma unroll
        for (int w8 = 1; w8 < 8; ++w8) {
            float4 pp = vwbuf[(w8*5 + v)*16 + (t & 15)];
            s.x += pp.x; s.y += pp.y; s.z += pp.z; s.w += pp.w;
        }
        ((float4*)vw_part)[(size_t)bid*80 + t] = s;
    }
}

// ---------------------------------------------------------------------------
// K1b: 276 blocks, 256 threads. (unchanged from R11, passing)
// blk<256: (b,h) -> transpose m_hw row; uh border = sum_v R / 320.
// blk>=256: (b,v) -> fold vw halves, transpose; uv border = sum_h R / 4096.
// ---------------------------------------------------------------------------
__global__ __launch_bounds__(256) void k1b_assemble(
        const float* __restrict__ m_hw, const float* __restrict__ R,
        const float* __restrict__ vw_part, float* __restrict__ grid_t) {
    __shared__ float tile[64][68];
    const int blk = blockIdx.x;
    const bool top = blk < 256;
    const int t = threadIdx.x;        // 0..255
    const int c = t >> 2;             // 0..63
    const int qs = t & 3;             // 0..3

    int b, i;
    if (top) {
        b = blk >> 6;
        const int h = blk & 63;
        i = h;
        #pragma unroll
        for (int j = 0; j < 4; ++j) {
            const int q = 4*j + qs;   // 0..15
            float4 v = ((const float4*)m_hw)[((size_t)(b*64 + c))*1024 + h*16 + q];
            const int w = q * 4;
            tile[w+0][c] = v.x; tile[w+1][c] = v.y;
            tile[w+2][c] = v.z; tile[w+3][c] = v.w;
        }
        // uh border: sum over v of R[bc][u*5+v][h], /320
        for (int idx = t; idx < 320; idx += 256) {
            const int u = idx >> 6, cc = idx & 63;
            const float* Rp = R + (((size_t)(b*64 + cc)*25) + u*5)*64 + h;
            float s = Rp[0] + Rp[64] + Rp[128] + Rp[192] + Rp[256];
            grid_t[((size_t)b*NIJ + h*69 + 64 + u)*64 + cc] = s * (1.f/320.f);
        }
    } else {
        b = (blk - 256) / 5;
        const int v = (blk - 256) % 5;
        i = 64 + v;
        #pragma unroll
        for (int j = 0; j < 4; ++j) {
            const int wq = 4*j + qs;
            float4 p0 = ((const float4*)vw_part)[((size_t)(b*64 + c)*2 + 0)*80 + v*16 + wq];
            float4 p1 = ((const float4*)vw_part)[((size_t)(b*64 + c)*2 + 1)*80 + v*16 + wq];
            const int w = wq * 4;
            const float sc = 1.f/320.f;
            tile[w+0][c] = (p0.x + p1.x)*sc; tile[w+1][c] = (p0.y + p1.y)*sc;
            tile[w+2][c] = (p0.z + p1.z)*sc; tile[w+3][c] = (p0.w + p1.w)*sc;
        }
        // uv border: sum over h of R[bc][u*5+v][h], /4096
        for (int idx = t; idx < 320; idx += 256) {
            const int u = idx >> 6, cc = idx & 63;
            const float4* Rp4 = (const float4*)(R + (((size_t)(b*64 + cc)*25) + u*5 + v)*64);
            float4 a = make_float4(0.f,0.f,0.f,0.f);
            #pragma unroll
            for (int k = 0; k < 16; ++k) {
                float4 pp = Rp4[k];
                a.x += pp.x; a.y += pp.y; a.z += pp.z; a.w += pp.w;
            }
            grid_t[((size_t)b*NIJ + i*69 + 64 + u)*64 + cc] = sum4(a) * (1.f/4096.f);
        }
    }
    __syncthreads();

    float4* dst4 = (float4*)grid_t + ((size_t)b*NIJ + i*69) * 16;
    #pragma unroll
    for (int k = 0; k < 4; ++k) {
        const int oidx = k*256 + t;   // 0..1023
        const int w = oidx >> 4, cq = (oidx & 15) * 4;
        float4 v;
        v.x = tile[w][cq]; v.y = tile[w][cq+1];
        v.z = tile[w][cq+2]; v.w = tile[w][cq+3];
        dst4[oidx] = v;
    }
}

// ---------------------------------------------------------------------------
// K2: per-position MLP + region conv. (unchanged, passing)
// grid = 1104 blocks, 64 threads. __launch_bounds__(64,1): weights in VGPRs.
// ---------------------------------------------------------------------------
#define LOADROW(dst, src)                                              \
    { _Pragma("unroll")                                                \
      for (int q = 0; q < 16; ++q) {                                   \
          float4 t4 = ((const float4*)(src))[lane*16 + q];             \
          dst[4*q+0] = t4.x; dst[4*q+1] = t4.y;                        \
          dst[4*q+2] = t4.z; dst[4*q+3] = t4.w;                        \
      } }

#define DOT64(res, wr, src)                                            \
    float res;                                                         \
    { float _a0=0.f,_a1=0.f,_a2=0.f,_a3=0.f;                           \
      _Pragma("unroll")                                                \
      for (int cc2 = 0; cc2 < 64; cc2 += 4) {                          \
          _a0 = fmaf(wr[cc2+0], rdlane(src, cc2+0), _a0);              \
          _a1 = fmaf(wr[cc2+1], rdlane(src, cc2+1), _a1);              \
          _a2 = fmaf(wr[cc2+2], rdlane(src, cc2+2), _a2);              \
          _a3 = fmaf(wr[cc2+3], rdlane(src, cc2+3), _a3);              \
      }                                                                \
      res = (_a0 + _a1) + (_a2 + _a3); }

#define MLP_BODY(J)                                                    \
    {                                                                  \
        const int jj = (J);                                            \
        float v = gtb[(size_t)(i*69 + jj) * CC + lane];                \
        DOT64(d1, w1r, v);                                             \
        float acc1 = d1 + b1v;                                         \
        float ya = acc1 / (1.f + __expf(-acc1));                       \
        DOT64(d2, w2r, ya);                                            \
        float acc2 = d2 + b2v;                                         \
        DOT64(d3, fr, acc2);                                           \
        sp[(size_t)(jj - jbase) * sstr] = d3 + fbv;                    \
    }

__global__ __launch_bounds__(64, 1) void k2_mlp(
        const float* __restrict__ grid_t,
        const float* __restrict__ w1, const float* __restrict__ b1,
        const float* __restrict__ w2, const float* __restrict__ b2,
        const float* __restrict__ fw0, const float* __restrict__ fb0,
        const float* __restrict__ fw1, const float* __restrict__ fb1,
        const float* __restrict__ fw2, const float* __restrict__ fb2,
        const float* __restrict__ fw3, const float* __restrict__ fb3,
        float* __restrict__ mod_hw, float* __restrict__ mod_uh,
        float* __restrict__ mod_vw, float* __restrict__ mod_uv) {
    const int blk  = blockIdx.x;          // row*4 + chunk
    const int row  = blk >> 2;            // 0..275
    const int chnk = blk & 3;
    const int b    = row / 69;
    const int i    = row % 69;
    const int lane = threadIdx.x & 63;

    const int j0 = chnk * 18;
    const int j1 = min(69, j0 + 18);
    const bool top = (i < 64);

    const float* fwA = top ? fw0 : fw3;
    const float* fbA = top ? fb0 : fb3;
    const float* fwB = top ? fw2 : fw1;
    const float* fbB = top ? fb2 : fb1;

    float w1r[64], w2r[64], fr[64];
    LOADROW(w1r, w1);
    LOADROW(w2r, w2);
    const float b1v = b1[lane];
    const float b2v = b2[lane];

    const float* gtb = grid_t + (size_t)b * NIJ * CC;
    const int cbl = b * CC + lane;

    const int jm = min(j1, 64);
    if (j0 < jm) {                        // region A: j < 64
        LOADROW(fr, fwA);
        const float fbv = fbA[lane];
        float* sp; int sstr; const int jbase = 0;
        if (top) { sp = mod_hw + ((size_t)cbl*64 + i)*64;          sstr = 1; }
        else     { sp = mod_vw + (size_t)cbl*320 + (i-64)*64;      sstr = 1; }
        for (int j = j0; j < jm; ++j) MLP_BODY(j)
    }
    if (j1 > 64) {                        // region B: j >= 64
        LOADROW(fr, fwB);
        const float fbv = fbB[lane];
        float* sp; int sstr; const int jbase = 64;
        if (top) { sp = mod_uh + (size_t)cbl*320 + i;              sstr = 64; }
        else     { sp = mod_uv + (size_t)cbl*25 + (i-64);          sstr = 5;  }
        const int jb = max(j0, 64);
        for (int j = jb; j < j1; ++j) MLP_BODY(j)
    }
}

// ---------------------------------------------------------------------------
// K3: out = x * (mod_hw + mod_uv + mod_uh + mod_vw) (unchanged, passing)
// 1024 blocks = (bc, quarter), 256 threads, 4 blocks/CU.
// ---------------------------------------------------------------------------
__global__ __launch_bounds__(256, 4) void k3_apply(
        const float* __restrict__ x,
        const float* __restrict__ mod_hw, const float* __restrict__ mod_uh,
        const float* __restrict__ mod_vw, const float* __restrict__ mod_uv,
        float* __restrict__ out) {
    const int blk  = blockIdx.x;          // bc*4 + quarter
    const int bc   = blk >> 2;
    const int qt   = blk & 3;
    const int t    = threadIdx.x;         // 0..255
    const int base = qt*256 + t;          // quad index in tile, 0..1023
    const int h    = base >> 4;           // 0..63

    float4 mh = ((const float4*)(mod_hw + (size_t)bc * 4096))[base];
    float uh[5];
    #pragma unroll
    for (int u = 0; u < 5; ++u) uh[u] = mod_uh[(size_t)bc*320 + u*64 + h];
    float4 vw[5];
    #pragma unroll
    for (int v = 0; v < 5; ++v)
        vw[v] = ((const float4*)(mod_vw + (size_t)bc*320 + v*64))[t & 15];
    float uv[25];
    #pragma unroll
    for (int k = 0; k < 25; ++k)
        uv[k] = rfl(mod_uv[(size_t)bc*25 + k]);   // uniform -> SGPR

    const float4* x4 = (const float4*)(x + (size_t)bc * (UU*VV*HH*WW));
    float4* o4 = (float4*)(out + (size_t)bc * (UU*VV*HH*WW));

    #pragma unroll
    for (int u = 0; u < 5; ++u) {
        #pragma unroll
        for (int v = 0; v < 5; ++v) {
            const int idx = (u*5 + v)*1024 + base;
            float4 xv = x4[idx];
            const float s = uh[u] + uv[u*5 + v];
            float4 r;
            r.x = xv.x * (mh.x + vw[v].x + s);
            r.y = xv.y * (mh.y + vw[v].y + s);
            r.z = xv.z * (mh.z + vw[v].z + s);
            r.w = xv.w * (mh.w + vw[v].w + s);
            nt_store4(r, &o4[idx]);
        }
    }
}

// ---------------------------------------------------------------------------
extern "C" void kernel_launch(void* const* d_in, const int* in_sizes, int n_in,
                              void* d_out, int out_size, void* d_ws, size_t ws_size,
                              hipStream_t stream) {
    const float* x   = (const float*)d_in[0];
    const float* w1  = (const float*)d_in[1];
    const float* b1  = (const float*)d_in[2];
    const float* w2  = (const float*)d_in[3];
    const float* b2  = (const float*)d_in[4];
    const float* fw0 = (const float*)d_in[5];
    const float* fb0 = (const float*)d_in[6];
    const float* fw1 = (const float*)d_in[7];
    const float* fb1 = (const float*)d_in[8];
    const float* fw2 = (const float*)d_in[9];
    const float* fb2 = (const float*)d_in[10];
    const float* fw3 = (const float*)d_in[11];
    const float* fb3 = (const float*)d_in[12];

    float* ws = (float*)d_ws;
    float* grid_t = ws;                        // 4*4761*64      = 1,218,816
    float* mod_hw = ws + 1218816;              // 256*4096       = 1,048,576
    float* mod_uh = mod_hw + 1048576;          // 256*320        =    81,920
    float* mod_vw = mod_uh + 81920;            // 256*320        =    81,920
    float* mod_uv = mod_vw + 81920;            // 256*25         =     6,400

    // d_out doubles as scratch for k1 outputs (k3 fully rewrites it).
    float* m_hw    = (float*)d_out;            // 256*4096       = 1,048,576
    float* Rbuf    = m_hw + 1048576;           // 256*25*64      =   409,600
    float* vw_part = Rbuf + 409600;            // 512*320        =   163,840

    k1_means<<<BB*CC*2, 512, 0, stream>>>(x, m_hw, Rbuf, vw_part);
    k1b_assemble<<<BB*CC + BB*VV, 256, 0, stream>>>(m_hw, Rbuf, vw_part, grid_t);
    k2_mlp<<<BB*69*4, 64, 0, stream>>>(grid_t, w1, b1, w2, b2,
                                       fw0, fb0, fw1, fb1, fw2, fb2, fw3, fb3,
                                       mod_hw, mod_uh, mod_vw, mod_uv);
    k3_apply<<<BB*CC*4, 256, 0, stream>>>(x, mod_hw, mod_uh, mod_vw, mod_uv,
                                          (float*)d_out);
}

// Round 13
// 100.380 us; speedup vs baseline: 1.4054x; 1.0757x over previous
//
#include <hip/hip_runtime.h>
#include <hip/hip_bf16.h>
#include <cstddef>

#define BB 4
#define CC 64
#define UU 5
#define VV 5
#define HH 64
#define WW 64

typedef float f4v __attribute__((ext_vector_type(4)));

__device__ __forceinline__ float rdlane(float v, int l) {
    return __uint_as_float((unsigned)__builtin_amdgcn_readlane((int)__float_as_uint(v), l));
}
__device__ __forceinline__ float rfl(float v) {
    return __uint_as_float((unsigned)__builtin_amdgcn_readfirstlane((int)__float_as_uint(v)));
}
__device__ __forceinline__ float sum4(float4 a) { return (a.x+a.y)+(a.z+a.w); }
__device__ __forceinline__ void nt_store4(float4 r, float4* p) {
    union { float4 s; f4v v; } u; u.s = r;
    __builtin_nontemporal_store(u.v, (f4v*)p);
}

// ---------------------------------------------------------------------------
// K1 (same as R12, passing): 512 blocks = (bc, half), 512 threads.
// Shuffle-free inner loop; reductions deferred behind one barrier.
//   m_hw[bc*4096 + h*64 + w]      final /25
//   R[(bc*25+k)*64 + h]           UNSCALED row sums (k = u*5+v)
//   vw_part[bid*320 + v*64 + w]   UNSCALED col sums over block's 32 h
// Scratch lives in d_out (k3 rewrites it).
// ---------------------------------------------------------------------------
__global__ __launch_bounds__(512) void k1_means(const float* __restrict__ x,
        float* __restrict__ m_hw, float* __restrict__ R,
        float* __restrict__ vw_part) {
    const int bid  = blockIdx.x;      // bc*2 + half
    const int bc   = bid >> 1;
    const int half = bid & 1;
    const int t    = threadIdx.x;     // 0..511
    const int p    = half*512 + t;    // quad index in tile, 0..1023
    const int wave = t >> 6;
    const int lane = t & 63;

    const float4* xt = (const float4*)x + (size_t)bc * 25600;

    __shared__ float smem[25*512];    // 51.2 KB: [tile][thread] quad-sums

    float4 hw = make_float4(0.f,0.f,0.f,0.f);
    float4 vwacc[5];
    #pragma unroll
    for (int v = 0; v < 5; ++v) vwacc[v] = make_float4(0.f,0.f,0.f,0.f);

    #pragma unroll
    for (int u = 0; u < 5; ++u) {
        #pragma unroll
        for (int v = 0; v < 5; ++v) {
            float4 q = xt[(u*5 + v)*1024 + p];
            hw.x += q.x; hw.y += q.y; hw.z += q.z; hw.w += q.w;
            vwacc[v].x += q.x; vwacc[v].y += q.y;
            vwacc[v].z += q.z; vwacc[v].w += q.w;
            smem[(u*5 + v)*512 + t] = sum4(q);   // fire-and-forget
        }
    }

    float4 o;
    o.x = hw.x*(1.f/25.f); o.y = hw.y*(1.f/25.f);
    o.z = hw.z*(1.f/25.f); o.w = hw.w*(1.f/25.f);
    ((float4*)m_hw)[(size_t)bc*1024 + p] = o;

    __syncthreads();

    // Phase B: R row-sums. 800 tasks = 25 tiles x 32 local h.
    for (int task = t; task < 800; task += 512) {
        const int k    = task >> 5;
        const int hloc = task & 31;
        const float* row = &smem[k*512 + hloc*16];
        float s = 0.f;
        #pragma unroll
        for (int j = 0; j < 16; ++j) s += row[j];
        R[((size_t)bc*25 + k)*64 + half*32 + hloc] = s;
    }
    __syncthreads();

    // Phase C: vw cross-lane fold (once), reuse smem
    float4* vwbuf = (float4*)smem;
    #pragma unroll
    for (int v = 0; v < 5; ++v) {
        float4 s = vwacc[v];
        s.x += __shfl_xor(s.x, 16); s.y += __shfl_xor(s.y, 16);
        s.z += __shfl_xor(s.z, 16); s.w += __shfl_xor(s.w, 16);
        s.x += __shfl_xor(s.x, 32); s.y += __shfl_xor(s.y, 32);
        s.z += __shfl_xor(s.z, 32); s.w += __shfl_xor(s.w, 32);
        if (lane < 16) vwbuf[(wave*5 + v)*16 + lane] = s;
    }
    __syncthreads();

    if (t < 80) {
        const int v = t >> 4;
        float4 s = vwbuf[(0*5 + v)*16 + (t & 15)];
        #pragma unroll
        for (int w8 = 1; w8 < 8; ++w8) {
            float4 pp = vwbuf[(w8*5 + v)*16 + (t & 15)];
            s.x += pp.x; s.y += pp.y; s.z += pp.z; s.w += pp.w;
        }
        ((float4*)vw_part)[(size_t)bid*80 + t] = s;
    }
}

// ---------------------------------------------------------------------------
// K2' (R13): per-position MLP + region conv, reading k1's channel-first
// buffers DIRECTLY (per-lane gathers; data is ~6.5MB, L2/L3-resident).
// Replaces k1b+k2. grid = 1104 blocks, 64 threads. (64,1): weights in VGPRs.
// Grid value at (i, j), channel c=lane:
//   top (i<64),  j<64 : m_hw[(b64+c)*4096 + i*64 + j]            (already /25)
//   top,         j>=64: sum_v R[((b64+c)*25 + (j-64)*5+v)*64 + i] / 320
//   bot (i>=64), j<64 : (vw_part[(b64+c)*2*320 + {0,320}] fold) / 320
//   bot,         j>=64: sum_h R[((b64+c)*25 + (j-64)*5+(i-64))*64 + h] / 4096
// ---------------------------------------------------------------------------
#define LOADROW(dst, src)                                              \
    { _Pragma("unroll")                                                \
      for (int q = 0; q < 16; ++q) {                                   \
          float4 t4 = ((const float4*)(src))[lane*16 + q];             \
          dst[4*q+0] = t4.x; dst[4*q+1] = t4.y;                        \
          dst[4*q+2] = t4.z; dst[4*q+3] = t4.w;                        \
      } }

#define DOT64(res, wr, src)                                            \
    float res;                                                         \
    { float _a0=0.f,_a1=0.f,_a2=0.f,_a3=0.f;                           \
      _Pragma("unroll")                                                \
      for (int cc2 = 0; cc2 < 64; cc2 += 4) {                          \
          _a0 = fmaf(wr[cc2+0], rdlane(src, cc2+0), _a0);              \
          _a1 = fmaf(wr[cc2+1], rdlane(src, cc2+1), _a1);              \
          _a2 = fmaf(wr[cc2+2], rdlane(src, cc2+2), _a2);              \
          _a3 = fmaf(wr[cc2+3], rdlane(src, cc2+3), _a3);              \
      }                                                                \
      res = (_a0 + _a1) + (_a2 + _a3); }

#define MLP_CORE(VIN, OUTEXPR)                                         \
    {                                                                  \
        float v = (VIN);                                               \
        DOT64(d1, w1r, v);                                             \
        float acc1 = d1 + b1v;                                         \
        float ya = acc1 / (1.f + __expf(-acc1));                       \
        DOT64(d2, w2r, ya);                                            \
        float acc2 = d2 + b2v;                                         \
        DOT64(d3, fr, acc2);                                           \
        OUTEXPR = d3 + fbv;                                            \
    }

__global__ __launch_bounds__(64, 1) void k2_mlp(
        const float* __restrict__ m_hw, const float* __restrict__ R,
        const float* __restrict__ vw_part,
        const float* __restrict__ w1, const float* __restrict__ b1,
        const float* __restrict__ w2, const float* __restrict__ b2,
        const float* __restrict__ fw0, const float* __restrict__ fb0,
        const float* __restrict__ fw1, const float* __restrict__ fb1,
        const float* __restrict__ fw2, const float* __restrict__ fb2,
        const float* __restrict__ fw3, const float* __restrict__ fb3,
        float* __restrict__ mod_hw, float* __restrict__ mod_uh,
        float* __restrict__ mod_vw, float* __restrict__ mod_uv) {
    const int blk  = blockIdx.x;          // row*4 + chunk
    const int row  = blk >> 2;            // 0..275
    const int chnk = blk & 3;
    const int b    = row / 69;
    const int i    = row % 69;
    const int lane = threadIdx.x & 63;

    const int j0 = chnk * 18;
    const int j1 = min(69, j0 + 18);
    const bool top = (i < 64);

    const float* fwA = top ? fw0 : fw3;
    const float* fbA = top ? fb0 : fb3;
    const float* fwB = top ? fw2 : fw1;
    const float* fbB = top ? fb2 : fb1;

    float w1r[64], w2r[64], fr[64];
    LOADROW(w1r, w1);
    LOADROW(w2r, w2);
    const float b1v = b1[lane];
    const float b2v = b2[lane];

    const int b64c = b * CC + lane;       // (b,c) slab index for gathers
    const int cbl  = b64c;                // output channel index with batch

    const int jm = min(j1, 64);
    if (j0 < jm) {                        // region A: j < 64
        LOADROW(fr, fwA);
        const float fbv = fbA[lane];
        if (top) {
            const float* src = m_hw + (size_t)b64c*4096 + i*64;
            float* sp = mod_hw + ((size_t)cbl*64 + i)*64;
            for (int j = j0; j < jm; ++j)
                MLP_CORE(src[j], sp[j])
        } else {
            const float* p0 = vw_part + (size_t)b64c*640 + (i-64)*64;   // half 0: vv*64... 
            // NOTE: vw_part float layout = bid*320 + v*64 + w, bid = bc*2+half
            const float* q0 = vw_part + ((size_t)b64c*2 + 0)*320 + (i-64)*64;
            const float* q1 = vw_part + ((size_t)b64c*2 + 1)*320 + (i-64)*64;
            float* sp = mod_vw + (size_t)cbl*320 + (i-64)*64;
            (void)p0;
            for (int j = j0; j < jm; ++j)
                MLP_CORE((q0[j] + q1[j]) * (1.f/320.f), sp[j])
        }
    }
    if (j1 > 64) {                        // region B: j >= 64
        LOADROW(fr, fwB);
        const float fbv = fbB[lane];
        const int jb = max(j0, 64);
        if (top) {
            float* sp = mod_uh + (size_t)cbl*320 + i;
            for (int j = jb; j < j1; ++j) {
                const int u = j - 64;
                const float* Rp = R + ((size_t)b64c*25 + u*5)*64 + i;
                float vin = (Rp[0] + Rp[64] + Rp[128] + Rp[192] + Rp[256])
                            * (1.f/320.f);
                MLP_CORE(vin, sp[(size_t)u*64])
            }
        } else {
            float* sp = mod_uv + (size_t)cbl*25 + (i-64);
            for (int j = jb; j < j1; ++j) {
                const int u = j - 64;
                const float4* Rp4 = (const float4*)(R
                    + ((size_t)b64c*25 + u*5 + (i-64))*64);
                float4 a = make_float4(0.f,0.f,0.f,0.f);
                #pragma unroll
                for (int k = 0; k < 16; ++k) {
                    float4 pp = Rp4[k];
                    a.x += pp.x; a.y += pp.y; a.z += pp.z; a.w += pp.w;
                }
                MLP_CORE(sum4(a) * (1.f/4096.f), sp[(size_t)u*5])
            }
        }
    }
}

// ---------------------------------------------------------------------------
// K3 (unchanged, passing): out = x * (mod_hw + mod_uv + mod_uh + mod_vw)
// 1024 blocks = (bc, quarter), 256 threads, 4 blocks/CU.
// ---------------------------------------------------------------------------
__global__ __launch_bounds__(256, 4) void k3_apply(
        const float* __restrict__ x,
        const float* __restrict__ mod_hw, const float* __restrict__ mod_uh,
        const float* __restrict__ mod_vw, const float* __restrict__ mod_uv,
        float* __restrict__ out) {
    const int blk  = blockIdx.x;          // bc*4 + quarter
    const int bc   = blk >> 2;
    const int qt   = blk & 3;
    const int t    = threadIdx.x;         // 0..255
    const int base = qt*256 + t;          // quad index in tile, 0..1023
    const int h    = base >> 4;           // 0..63

    float4 mh = ((const float4*)(mod_hw + (size_t)bc * 4096))[base];
    float uh[5];
    #pragma unroll
    for (int u = 0; u < 5; ++u) uh[u] = mod_uh[(size_t)bc*320 + u*64 + h];
    float4 vw[5];
    #pragma unroll
    for (int v = 0; v < 5; ++v)
        vw[v] = ((const float4*)(mod_vw + (size_t)bc*320 + v*64))[t & 15];
    float uv[25];
    #pragma unroll
    for (int k = 0; k < 25; ++k)
        uv[k] = rfl(mod_uv[(size_t)bc*25 + k]);   // uniform -> SGPR

    const float4* x4 = (const float4*)(x + (size_t)bc * (UU*VV*HH*WW));
    float4* o4 = (float4*)(out + (size_t)bc * (UU*VV*HH*WW));

    #pragma unroll
    for (int u = 0; u < 5; ++u) {
        #pragma unroll
        for (int v = 0; v < 5; ++v) {
            const int idx = (u*5 + v)*1024 + base;
            float4 xv = x4[idx];
            const float s = uh[u] + uv[u*5 + v];
            float4 r;
            r.x = xv.x * (mh.x + vw[v].x + s);
            r.y = xv.y * (mh.y + vw[v].y + s);
            r.z = xv.z * (mh.z + vw[v].z + s);
            r.w = xv.w * (mh.w + vw[v].w + s);
            nt_store4(r, &o4[idx]);
        }
    }
}

// ---------------------------------------------------------------------------
extern "C" void kernel_launch(void* const* d_in, const int* in_sizes, int n_in,
                              void* d_out, int out_size, void* d_ws, size_t ws_size,
                              hipStream_t stream) {
    const float* x   = (const float*)d_in[0];
    const float* w1  = (const float*)d_in[1];
    const float* b1  = (const float*)d_in[2];
    const float* w2  = (const float*)d_in[3];
    const float* b2  = (const float*)d_in[4];
    const float* fw0 = (const float*)d_in[5];
    const float* fb0 = (const float*)d_in[6];
    const float* fw1 = (const float*)d_in[7];
    const float* fb1 = (const float*)d_in[8];
    const float* fw2 = (const float*)d_in[9];
    const float* fb2 = (const float*)d_in[10];
    const float* fw3 = (const float*)d_in[11];
    const float* fb3 = (const float*)d_in[12];

    float* ws = (float*)d_ws;
    float* mod_hw = ws;                        // 256*4096       = 1,048,576
    float* mod_uh = mod_hw + 1048576;          // 256*320        =    81,920
    float* mod_vw = mod_uh + 81920;            // 256*320        =    81,920
    float* mod_uv = mod_vw + 81920;            // 256*25         =     6,400

    // d_out doubles as scratch for k1 outputs (k3 fully rewrites it).
    float* m_hw    = (float*)d_out;            // 256*4096       = 1,048,576
    float* Rbuf    = m_hw + 1048576;           // 256*25*64      =   409,600
    float* vw_part = Rbuf + 409600;            // 512*320        =   163,840

    k1_means<<<BB*CC*2, 512, 0, stream>>>(x, m_hw, Rbuf, vw_part);
    k2_mlp<<<BB*69*4, 64, 0, stream>>>(m_hw, Rbuf, vw_part, w1, b1, w2, b2,
                                       fw0, fb0, fw1, fb1, fw2, fb2, fw3, fb3,
                                       mod_hw, mod_uh, mod_vw, mod_uv);
    k3_apply<<<BB*CC*4, 256, 0, stream>>>(x, mod_hw, mod_uh, mod_vw, mod_uv,
                                          (float*)d_out);
}